// Round 3
// baseline (21888.472 us; speedup 1.0000x reference)
//
#include <hip/hip_runtime.h>
#include <hip/hip_fp16.h>

// Entropic OT (Sinkhorn), B=64, n=m=1024, d=64, eps=0.1, 50 iters.
// q[b,i,j] = <s_i,t_j> (unit rows) stored once as fp16 (128 MiB, LLC-resident).
// cost = 2-2q exactly. All math in log2 domain: log2 K = CK*q - CK.
//
// FUSED iteration (one q-pass per Sinkhorn iteration, 50 total):
//   wave computes row-LSE lu_i in registers (lane holds 16 columns of the row),
//   then reuses the same in-register t values for the column-sum accumulation:
//     e_ij = 2^{CKq - CK + lu_i} = t_ij * iw_j * g_i,
//   t = 2^{CKq+w} (row phase), iw_j = 2^{-w_j} = sv_j * 2^{CK+10} (per pass),
//   g_i = 2^{lu_i-CK} = 2^{-10-CK}/s_i (one rcp per row). No exp2 in col phase,
//   no log2 for lu, lu never stored. Column partials acc[16] in registers,
//   one atomicAdd per column per wave per pass (64 adds/address/pass).
// Buffer rotation (3x raw-colsum buffers): pass t reads pp[(t+2)%3], writes
// pp[t%3], zeroes pp[(t+1)%3] for pass t+1. Pass 49 also accumulates the
// cost-weighted colsum ccol; answer = sum_j ccol_j/pcol_j / 65536.

#define BATCH 64
#define NPT   1024
#define DIM   64
#define CKF   28.853900817779268f    // 20 * log2(e)
#define NEG10 (-10.0f)
#define C2F   4.9680698566e11f       // 2^(CK+10)  = 1024 * e^20
#define C3F   2.0128528582e-12f      // 2^(-10-CK) = 1/(1024 * e^20)

#if __has_builtin(__builtin_amdgcn_exp2f)
#define EXP2F(x) __builtin_amdgcn_exp2f(x)
#else
#define EXP2F(x) exp2f(x)
#endif

__device__ __forceinline__ float2 h2tof2(unsigned int u) {
  return __half22float2(__builtin_bit_cast(__half2, u));
}
__device__ __forceinline__ void dec8(uint4 pk, float* f) {
  float2 t;
  t = h2tof2(pk.x); f[0] = t.x; f[1] = t.y;
  t = h2tof2(pk.y); f[2] = t.x; f[3] = t.y;
  t = h2tof2(pk.z); f[4] = t.x; f[5] = t.y;
  t = h2tof2(pk.w); f[6] = t.x; f[7] = t.y;
}

// ---------------------------------------------------------------------------
// build_q: per-batch GEMM dot[i,j] = <s_i/|s_i|, t_j/|t_j|>, fp16 out.
// (unchanged from R1: 148 us, 3-10% of total; revisit once passes are fast)
// ---------------------------------------------------------------------------
__global__ __launch_bounds__(256) void build_q(
    const float* __restrict__ src, const float* __restrict__ tgt,
    __half* __restrict__ q)
{
  __shared__ float sA[DIM][68];
  __shared__ float sB[DIM][68];

  const int b    = blockIdx.x >> 8;
  const int tile = blockIdx.x & 255;
  const int i0 = (tile >> 4) << 6;
  const int j0 = (tile & 15) << 6;
  const int tid = threadIdx.x;
  const int r = tid >> 2;
  const int c = tid & 3;

  {
    const float4* p4 = (const float4*)(src + ((size_t)b * NPT + (i0 + r)) * DIM + c * 16);
    float4 a0 = p4[0], a1 = p4[1], a2 = p4[2], a3 = p4[3];
    float v[16] = {a0.x,a0.y,a0.z,a0.w, a1.x,a1.y,a1.z,a1.w,
                   a2.x,a2.y,a2.z,a2.w, a3.x,a3.y,a3.z,a3.w};
    float ss = 0.f;
    #pragma unroll
    for (int k = 0; k < 16; ++k) ss = fmaf(v[k], v[k], ss);
    ss += __shfl_xor(ss, 1);
    ss += __shfl_xor(ss, 2);
    const float sc = 1.0f / fmaxf(sqrtf(ss), 1e-12f);
    #pragma unroll
    for (int k = 0; k < 16; ++k) sA[c * 16 + k][r] = v[k] * sc;
  }
  {
    const float4* p4 = (const float4*)(tgt + ((size_t)b * NPT + (j0 + r)) * DIM + c * 16);
    float4 a0 = p4[0], a1 = p4[1], a2 = p4[2], a3 = p4[3];
    float v[16] = {a0.x,a0.y,a0.z,a0.w, a1.x,a1.y,a1.z,a1.w,
                   a2.x,a2.y,a2.z,a2.w, a3.x,a3.y,a3.z,a3.w};
    float ss = 0.f;
    #pragma unroll
    for (int k = 0; k < 16; ++k) ss = fmaf(v[k], v[k], ss);
    ss += __shfl_xor(ss, 1);
    ss += __shfl_xor(ss, 2);
    const float sc = 1.0f / fmaxf(sqrtf(ss), 1e-12f);
    #pragma unroll
    for (int k = 0; k < 16; ++k) sB[c * 16 + k][r] = v[k] * sc;
  }
  __syncthreads();

  const int mi = (tid >> 4) << 2;
  const int mj = (tid & 15) << 2;
  float acc[4][4] = {};
  #pragma unroll 16
  for (int d = 0; d < DIM; ++d) {
    const float4 a = *(const float4*)&sA[d][mi];
    const float4 t = *(const float4*)&sB[d][mj];
    const float av[4] = {a.x, a.y, a.z, a.w};
    const float tv[4] = {t.x, t.y, t.z, t.w};
    #pragma unroll
    for (int ii = 0; ii < 4; ++ii)
      #pragma unroll
      for (int jj = 0; jj < 4; ++jj)
        acc[ii][jj] = fmaf(av[ii], tv[jj], acc[ii][jj]);
  }

  #pragma unroll
  for (int ii = 0; ii < 4; ++ii) {
    __half2 h0 = __floats2half2_rn(acc[ii][0], acc[ii][1]);
    __half2 h1 = __floats2half2_rn(acc[ii][2], acc[ii][3]);
    uint2 pk = { __builtin_bit_cast(unsigned int, h0),
                 __builtin_bit_cast(unsigned int, h1) };
    *(uint2*)(q + (size_t)b * NPT * NPT
                + (size_t)(i0 + mi + ii) * NPT + (j0 + mj)) = pk;
  }
}

// ---------------------------------------------------------------------------
// sink_pass<FIRST,FINAL>: one full Sinkhorn iteration in one q-pass.
// 1024 blocks (16/batch) x 256 thr; wave processes 16 rows; lane owns 16 cols.
// ---------------------------------------------------------------------------
template<bool FIRST, bool FINAL>
__global__ __launch_bounds__(256, 4) void sink_pass(
    const __half* __restrict__ q,
    const float* __restrict__ pR,   // raw colsums from prev iter (if !FIRST)
    float* __restrict__ pW,         // colsum accumulator (pre-zeroed)
    float* __restrict__ pZ,         // buffer to zero for next iter
    float* __restrict__ ccol)       // cost-weighted colsums (FINAL only)
{
  const int b    = blockIdx.x >> 4;
  const int rblk = blockIdx.x & 15;
  const int lane = threadIdx.x & 63;
  const int wave = threadIdx.x >> 6;

  // zero the next iteration's accumulator slice (no readers/writers this pass)
  if (threadIdx.x < 64)
    pZ[((size_t)b << 10) + (rblk << 6) + threadIdx.x] = 0.f;

  // per-lane column weights: w[k] = lv_j - CK, iw[k] = 2^{-w[k]}
  float w[16], iw[16];
  if (FIRST) {
    #pragma unroll
    for (int k = 0; k < 16; ++k) { w[k] = -CKF; iw[k] = 1.0f / C3F * (1.0f / 1024.0f); }
    // iw = 2^{CK} = e^20 = C2F/1024
  } else {
    const float4* wp = (const float4*)(pR + ((size_t)b << 10) + lane * 16);
    const float4 s0 = wp[0], s1 = wp[1], s2 = wp[2], s3 = wp[3];
    const float sv[16] = {s0.x,s0.y,s0.z,s0.w, s1.x,s1.y,s1.z,s1.w,
                          s2.x,s2.y,s2.z,s2.w, s3.x,s3.y,s3.z,s3.w};
    #pragma unroll
    for (int k = 0; k < 16; ++k) {
      w[k]  = (NEG10 - CKF) - log2f(sv[k]);  // lv_j - CK
      iw[k] = sv[k] * C2F;                   // 2^{-w} = sv * 2^{CK+10}
    }
  }

  float acc[16] = {};
  float cacc[16];
  if (FINAL) {
    #pragma unroll
    for (int k = 0; k < 16; ++k) cacc[k] = 0.f;
  }

  const __half* qb = q + ((size_t)b << 20);
  #define ROWP(rr) ((const uint4*)(qb + ((size_t)((rblk << 6) + ((rr) << 2) + wave) << 10) + lane * 16))

  uint4 pa = ROWP(0)[0], pb = ROWP(0)[1];
  #pragma unroll
  for (int rr = 0; rr < 16; ++rr) {
    uint4 na, nb;
    if (rr < 15) { na = ROWP(rr + 1)[0]; nb = ROWP(rr + 1)[1]; }

    float f[16];
    dec8(pa, f);
    dec8(pb, f + 8);

    // row phase: t_k = 2^{CK q + w_k}, s = sum_k t_k
    float t[16];
    #pragma unroll
    for (int k = 0; k < 16; ++k) t[k] = EXP2F(fmaf(f[k], CKF, w[k]));
    float s0 = (t[0] + t[1]) + (t[2] + t[3]);
    float s1 = (t[4] + t[5]) + (t[6] + t[7]);
    float s2 = (t[8] + t[9]) + (t[10] + t[11]);
    float s3 = (t[12] + t[13]) + (t[14] + t[15]);
    float s = (s0 + s1) + (s2 + s3);
    #pragma unroll
    for (int m = 1; m <= 32; m <<= 1) s += __shfl_xor(s, m);

    // g = 2^{lu - CK} = 2^{-10-CK} / s   (no exp2/log2 needed)
    const float g = C3F / s;

    // col phase: e_k = t_k * iw_k * g = 2^{CKq - CK + lu}
    #pragma unroll
    for (int k = 0; k < 16; ++k) {
      const float e = (t[k] * iw[k]) * g;
      acc[k] += e;
      if (FINAL) cacc[k] = fmaf(e, fmaf(f[k], -2.0f, 2.0f), cacc[k]);
    }
    pa = na; pb = nb;
  }
  #undef ROWP

  float* pc = pW + ((size_t)b << 10) + lane * 16;
  #pragma unroll
  for (int k = 0; k < 16; ++k) atomicAdd(&pc[k], acc[k]);
  if (FINAL) {
    float* cc = ccol + ((size_t)b << 10) + lane * 16;
    #pragma unroll
    for (int k = 0; k < 16; ++k) atomicAdd(&cc[k], cacc[k]);
  }
}

// ---------------------------------------------------------------------------
// final: mean_b sum_j ccol/pcol * 2^-10 / 64  ( = /65536 )
// ---------------------------------------------------------------------------
__global__ __launch_bounds__(256) void final_reduce(
    const float* __restrict__ pcol, const float* __restrict__ ccol,
    float* __restrict__ out)
{
  const int b = blockIdx.x;
  float s = 0.f;
  for (int j = threadIdx.x; j < NPT; j += 256) {
    const size_t k = ((size_t)b << 10) + j;
    s += ccol[k] / pcol[k];
  }
  #pragma unroll
  for (int m = 1; m <= 32; m <<= 1) s += __shfl_xor(s, m);
  __shared__ float ls[4];
  if ((threadIdx.x & 63) == 0) ls[threadIdx.x >> 6] = s;
  __syncthreads();
  if (threadIdx.x == 0)
    atomicAdd(out, (ls[0] + ls[1] + ls[2] + ls[3]) * (1.0f / 65536.0f));
}

// ---------------------------------------------------------------------------
extern "C" void kernel_launch(void* const* d_in, const int* in_sizes, int n_in,
                              void* d_out, int out_size, void* d_ws, size_t ws_size,
                              hipStream_t stream)
{
  (void)in_sizes; (void)n_in; (void)out_size; (void)ws_size;
  const float* src = (const float*)d_in[0];
  const float* tgt = (const float*)d_in[1];

  char* ws = (char*)d_ws;
  __half* q = (__half*)ws;                                    // 128 MiB
  const size_t QB = (size_t)BATCH * NPT * NPT * sizeof(__half);
  float* pp0  = (float*)(ws + QB);                            // 3 x 256 KB
  float* pp1  = pp0 + BATCH * NPT;
  float* pp2  = pp1 + BATCH * NPT;
  float* ccol = pp2 + BATCH * NPT;                            // 256 KB
  float* pp[3] = {pp0, pp1, pp2};

  hipMemsetAsync(pp0, 0, 4 * BATCH * NPT * sizeof(float), stream);
  hipMemsetAsync(d_out, 0, sizeof(float), stream);

  build_q<<<BATCH * 256, 256, 0, stream>>>(src, tgt, q);

  for (int t = 0; t < 50; ++t) {
    float* R = pp[(t + 2) % 3];
    float* W = pp[t % 3];
    float* Z = pp[(t + 1) % 3];
    if (t == 0)
      sink_pass<true, false><<<BATCH * 16, 256, 0, stream>>>(q, nullptr, W, Z, nullptr);
    else if (t == 49)
      sink_pass<false, true><<<BATCH * 16, 256, 0, stream>>>(q, R, W, Z, ccol);
    else
      sink_pass<false, false><<<BATCH * 16, 256, 0, stream>>>(q, R, W, Z, nullptr);
  }

  final_reduce<<<BATCH, 256, 0, stream>>>(pp[49 % 3], ccol, (float*)d_out);
}

// Round 4
// 11202.011 us; speedup vs baseline: 1.9540x; 1.9540x over previous
//
#include <hip/hip_runtime.h>
#include <hip/hip_fp16.h>

// Entropic OT (Sinkhorn), B=64, n=m=1024, d=64, eps=0.1, 50 iters.
// q[b,i,j] = <s_i,t_j> (unit rows) stored once as fp16 (128 MiB, LLC-resident).
// cost = 2-2q exactly. log2 K = CK*q - CK, CK = 20*log2(e).
//
// FUSED pass (one q-pass per Sinkhorn iteration, 50 total), R4 fixes:
//  * minimal register state: u = 2^{CK q}; persistent per-lane arrays only
//    wv[16] = 2^{lv-CK} and acc[16]; row: s = sum u*wv -> g = 2^-10/s;
//    col: acc += u*g, scaled by wv once in epilogue. No log2/exp2 for
//    potentials (1 div per row / per column).  ~90 live VGPRs.
//  * amdgpu_waves_per_eu(4,4): pin allocator at 128-VGPR budget (R3 chose
//    64 and spilled 651 MB/dispatch to scratch).
//  * LDS pipeline: 8x1024 fp16 tiles (16 KB) double-buffered via
//    global_load_lds width=16; {__syncthreads; stage(t+1); compute(t)} --
//    syncthreads' implicit vmcnt(0) == "tile t done" (t+1 not yet issued).
//    64 KB/CU in flight vs R2's ~512 B -> latency-bound 2.9 TB/s fixed.

#define BATCH 64
#define NPT   1024
#define DIM   64
#define CKF   28.853900817779268f    // 20 * log2(e)
#define WV0F  2.0611536224e-9f       // 2^{-CK}    = e^-20   (lv=0 first pass)
#define C3F   2.0128528582e-12f      // 2^{-10-CK}
#define G10F  0.0009765625f          // 2^-10

#if __has_builtin(__builtin_amdgcn_exp2f)
#define EXP2F(x) __builtin_amdgcn_exp2f(x)
#else
#define EXP2F(x) exp2f(x)
#endif

__device__ __forceinline__ float2 h2tof2(unsigned int u) {
  return __half22float2(__builtin_bit_cast(__half2, u));
}
__device__ __forceinline__ void dec8(uint4 pk, float* f) {
  float2 t;
  t = h2tof2(pk.x); f[0] = t.x; f[1] = t.y;
  t = h2tof2(pk.y); f[2] = t.x; f[3] = t.y;
  t = h2tof2(pk.z); f[4] = t.x; f[5] = t.y;
  t = h2tof2(pk.w); f[6] = t.x; f[7] = t.y;
}
__device__ __forceinline__ void stage16(const __half* g, __half* l) {
  __builtin_amdgcn_global_load_lds(
      (const __attribute__((address_space(1))) void*)g,
      (__attribute__((address_space(3))) void*)l, 16, 0, 0);
}

// ---------------------------------------------------------------------------
// build_q: per-batch GEMM dot[i,j] = <s_i/|s_i|, t_j/|t_j|>, fp16 out.
// (unchanged known-good; 148 us. Revisit after pass pipeline is verified.)
// ---------------------------------------------------------------------------
__global__ __launch_bounds__(256) void build_q(
    const float* __restrict__ src, const float* __restrict__ tgt,
    __half* __restrict__ q)
{
  __shared__ float sA[DIM][68];
  __shared__ float sB[DIM][68];

  const int b    = blockIdx.x >> 8;
  const int tile = blockIdx.x & 255;
  const int i0 = (tile >> 4) << 6;
  const int j0 = (tile & 15) << 6;
  const int tid = threadIdx.x;
  const int r = tid >> 2;
  const int c = tid & 3;

  {
    const float4* p4 = (const float4*)(src + ((size_t)b * NPT + (i0 + r)) * DIM + c * 16);
    float4 a0 = p4[0], a1 = p4[1], a2 = p4[2], a3 = p4[3];
    float v[16] = {a0.x,a0.y,a0.z,a0.w, a1.x,a1.y,a1.z,a1.w,
                   a2.x,a2.y,a2.z,a2.w, a3.x,a3.y,a3.z,a3.w};
    float ss = 0.f;
    #pragma unroll
    for (int k = 0; k < 16; ++k) ss = fmaf(v[k], v[k], ss);
    ss += __shfl_xor(ss, 1);
    ss += __shfl_xor(ss, 2);
    const float sc = 1.0f / fmaxf(sqrtf(ss), 1e-12f);
    #pragma unroll
    for (int k = 0; k < 16; ++k) sA[c * 16 + k][r] = v[k] * sc;
  }
  {
    const float4* p4 = (const float4*)(tgt + ((size_t)b * NPT + (j0 + r)) * DIM + c * 16);
    float4 a0 = p4[0], a1 = p4[1], a2 = p4[2], a3 = p4[3];
    float v[16] = {a0.x,a0.y,a0.z,a0.w, a1.x,a1.y,a1.z,a1.w,
                   a2.x,a2.y,a2.z,a2.w, a3.x,a3.y,a3.z,a3.w};
    float ss = 0.f;
    #pragma unroll
    for (int k = 0; k < 16; ++k) ss = fmaf(v[k], v[k], ss);
    ss += __shfl_xor(ss, 1);
    ss += __shfl_xor(ss, 2);
    const float sc = 1.0f / fmaxf(sqrtf(ss), 1e-12f);
    #pragma unroll
    for (int k = 0; k < 16; ++k) sB[c * 16 + k][r] = v[k] * sc;
  }
  __syncthreads();

  const int mi = (tid >> 4) << 2;
  const int mj = (tid & 15) << 2;
  float acc[4][4] = {};
  #pragma unroll 16
  for (int d = 0; d < DIM; ++d) {
    const float4 a = *(const float4*)&sA[d][mi];
    const float4 t = *(const float4*)&sB[d][mj];
    const float av[4] = {a.x, a.y, a.z, a.w};
    const float tv[4] = {t.x, t.y, t.z, t.w};
    #pragma unroll
    for (int ii = 0; ii < 4; ++ii)
      #pragma unroll
      for (int jj = 0; jj < 4; ++jj)
        acc[ii][jj] = fmaf(av[ii], tv[jj], acc[ii][jj]);
  }

  #pragma unroll
  for (int ii = 0; ii < 4; ++ii) {
    __half2 h0 = __floats2half2_rn(acc[ii][0], acc[ii][1]);
    __half2 h1 = __floats2half2_rn(acc[ii][2], acc[ii][3]);
    uint2 pk = { __builtin_bit_cast(unsigned int, h0),
                 __builtin_bit_cast(unsigned int, h1) };
    *(uint2*)(q + (size_t)b * NPT * NPT
                + (size_t)(i0 + mi + ii) * NPT + (j0 + mj)) = pk;
  }
}

// ---------------------------------------------------------------------------
// sink_pass<FIRST,FINAL>: one full Sinkhorn iteration in one q-pass.
// Grid: 1024 blocks (16/batch, 64 rows each) x 256 thr. Lane owns 16 cols.
// ---------------------------------------------------------------------------
template<bool FIRST, bool FINAL>
__global__ __launch_bounds__(256)
__attribute__((amdgpu_waves_per_eu(4, 4)))
void sink_pass(const __half* __restrict__ q,
               const float* __restrict__ pR,   // prev raw colsums (if !FIRST)
               float* __restrict__ pW,         // colsum accumulator (zeroed)
               float* __restrict__ pZ,         // buffer to zero for next iter
               float* __restrict__ ccol)       // cost-weighted colsums (FINAL)
{
  __shared__ __align__(16) __half smem[2][8][NPT];   // 2 x 16 KB

  const int b    = blockIdx.x >> 4;
  const int rblk = blockIdx.x & 15;
  const int lane = threadIdx.x & 63;
  const int wave = threadIdx.x >> 6;

  // zero next iteration's accumulator slice (no other readers/writers now)
  if (threadIdx.x < 64)
    pZ[((size_t)b << 10) + (rblk << 6) + threadIdx.x] = 0.f;

  // wv[k] = 2^{lv_j - CK} for this lane's 16 columns
  float wv[16];
  if (FIRST) {
    #pragma unroll
    for (int k = 0; k < 16; ++k) wv[k] = WV0F;
  } else {
    const float4* wp = (const float4*)(pR + ((size_t)b << 10) + lane * 16);
    const float4 s0 = wp[0], s1 = wp[1], s2 = wp[2], s3 = wp[3];
    const float sv[16] = {s0.x,s0.y,s0.z,s0.w, s1.x,s1.y,s1.z,s1.w,
                          s2.x,s2.y,s2.z,s2.w, s3.x,s3.y,s3.z,s3.w};
    #pragma unroll
    for (int k = 0; k < 16; ++k) wv[k] = C3F / sv[k];
  }

  float acc[16] = {};
  float cacc[16];
  if (FINAL) {
    #pragma unroll
    for (int k = 0; k < 16; ++k) cacc[k] = 0.f;
  }

  // 64-row slab of this block
  const __half* qt = q + ((size_t)b << 20) + ((size_t)(rblk << 6) << 10);

  // stage tile 0
  {
    const __half* gsrc = qt + (wave << 11) + (lane << 3);
    __half* ldst = &smem[0][0][0] + (wave << 11);
    #pragma unroll
    for (int p = 0; p < 4; ++p)
      stage16(gsrc + (p << 9), ldst + (p << 9));
  }

  #pragma unroll 2
  for (int t = 0; t < 8; ++t) {
    __syncthreads();   // implicit vmcnt(0): tile t landed; all threads synced
    if (t < 7) {       // stage tile t+1 into the other buffer (overlaps compute)
      const __half* gsrc = qt + ((size_t)(t + 1) << 13) + (wave << 11) + (lane << 3);
      __half* ldst = &smem[(t + 1) & 1][0][0] + (wave << 11);
      #pragma unroll
      for (int p = 0; p < 4; ++p)
        stage16(gsrc + (p << 9), ldst + (p << 9));
    }
    // compute tile t: wave handles rows 2w, 2w+1
    #pragma unroll
    for (int rr = 0; rr < 2; ++rr) {
      const uint4* rp = (const uint4*)&smem[t & 1][(wave << 1) + rr][0] + (lane << 1);
      const uint4 pa = rp[0];
      const uint4 pb = rp[1];
      float f[16];
      dec8(pa, f);
      dec8(pb, f + 8);
      float u[16];
      #pragma unroll
      for (int k = 0; k < 16; ++k) u[k] = EXP2F(f[k] * CKF);

      float d0 = 0.f, d1 = 0.f, d2 = 0.f, d3 = 0.f;
      #pragma unroll
      for (int k = 0; k < 16; k += 4) {
        d0 = fmaf(u[k],     wv[k],     d0);
        d1 = fmaf(u[k + 1], wv[k + 1], d1);
        d2 = fmaf(u[k + 2], wv[k + 2], d2);
        d3 = fmaf(u[k + 3], wv[k + 3], d3);
      }
      float s = (d0 + d1) + (d2 + d3);
      #pragma unroll
      for (int m = 1; m <= 32; m <<= 1) s += __shfl_xor(s, m);
      const float g = G10F / s;   // 2^{lu_i}

      #pragma unroll
      for (int k = 0; k < 16; ++k) {
        acc[k] = fmaf(u[k], g, acc[k]);
        if (FINAL) cacc[k] = fmaf(u[k] * g, fmaf(f[k], -2.0f, 2.0f), cacc[k]);
      }
    }
  }

  float* pc = pW + ((size_t)b << 10) + lane * 16;
  #pragma unroll
  for (int k = 0; k < 16; ++k) atomicAdd(&pc[k], acc[k] * wv[k]);
  if (FINAL) {
    float* cc = ccol + ((size_t)b << 10) + lane * 16;
    #pragma unroll
    for (int k = 0; k < 16; ++k) atomicAdd(&cc[k], cacc[k] * wv[k]);
  }
}

// ---------------------------------------------------------------------------
// final: mean_b sum_j ccol/pcol * 2^-10 / 64  ( = /65536 )
// ---------------------------------------------------------------------------
__global__ __launch_bounds__(256) void final_reduce(
    const float* __restrict__ pcol, const float* __restrict__ ccol,
    float* __restrict__ out)
{
  const int b = blockIdx.x;
  float s = 0.f;
  for (int j = threadIdx.x; j < NPT; j += 256) {
    const size_t k = ((size_t)b << 10) + j;
    s += ccol[k] / pcol[k];
  }
  #pragma unroll
  for (int m = 1; m <= 32; m <<= 1) s += __shfl_xor(s, m);
  __shared__ float ls[4];
  if ((threadIdx.x & 63) == 0) ls[threadIdx.x >> 6] = s;
  __syncthreads();
  if (threadIdx.x == 0)
    atomicAdd(out, (ls[0] + ls[1] + ls[2] + ls[3]) * (1.0f / 65536.0f));
}

// ---------------------------------------------------------------------------
extern "C" void kernel_launch(void* const* d_in, const int* in_sizes, int n_in,
                              void* d_out, int out_size, void* d_ws, size_t ws_size,
                              hipStream_t stream)
{
  (void)in_sizes; (void)n_in; (void)out_size; (void)ws_size;
  const float* src = (const float*)d_in[0];
  const float* tgt = (const float*)d_in[1];

  char* ws = (char*)d_ws;
  __half* q = (__half*)ws;                                    // 128 MiB
  const size_t QB = (size_t)BATCH * NPT * NPT * sizeof(__half);
  float* pp0  = (float*)(ws + QB);                            // 3 x 256 KB
  float* pp1  = pp0 + BATCH * NPT;
  float* pp2  = pp1 + BATCH * NPT;
  float* ccol = pp2 + BATCH * NPT;                            // 256 KB
  float* pp[3] = {pp0, pp1, pp2};

  hipMemsetAsync(pp0, 0, 4 * BATCH * NPT * sizeof(float), stream);
  hipMemsetAsync(d_out, 0, sizeof(float), stream);

  build_q<<<BATCH * 256, 256, 0, stream>>>(src, tgt, q);

  for (int t = 0; t < 50; ++t) {
    float* R = pp[(t + 2) % 3];
    float* W = pp[t % 3];
    float* Z = pp[(t + 1) % 3];
    if (t == 0)
      sink_pass<true, false><<<BATCH * 16, 256, 0, stream>>>(q, nullptr, W, Z, nullptr);
    else if (t == 49)
      sink_pass<false, true><<<BATCH * 16, 256, 0, stream>>>(q, R, W, Z, ccol);
    else
      sink_pass<false, false><<<BATCH * 16, 256, 0, stream>>>(q, R, W, Z, nullptr);
  }

  final_reduce<<<BATCH, 256, 0, stream>>>(pp[49 % 3], ccol, (float*)d_out);
}

// Round 5
// 2064.658 us; speedup vs baseline: 10.6015x; 5.4256x over previous
//
#include <hip/hip_runtime.h>
#include <hip/hip_fp16.h>

// Entropic OT (Sinkhorn), B=64, n=m=1024, d=64, eps=0.1, 50 iters.
// q[b,i,j] = <s_i,t_j> (unit rows) stored once as fp16 (128 MiB, LLC-resident).
// cost = 2-2q exactly. log2 K = CK*q - CK, CK = 20*log2(e).
//
// Clean invariant (R5): pass stores RAW column sums A_j = sum_i u_ij * g_i
// (u = 2^{CK q}, g_i = 2^{-10}/s_i = 2^{lu_i}); next pass's column weight is
// exactly wv_j = 2^{lv_j - CK} = 2^{-10} / A_j. No atomics anywhere in the
// iteration (R4 was bound by ~1024 serialized 64B-line atomic RMWs per cache
// line per pass = ~430us): per block, the 4 waves' acc[16] are LDS-combined
// (overlaying the staging buffers post-compute) and written as ONE coalesced
// 4KB slab-partial store: part[slab][b][1024]. Next pass's prologue sums the
// 16 slab partials per lane (L2-hot). Double-buffered partials across passes;
// pass 49 additionally emits cost-weighted partials cpart.
// Answer = 2^-10 * mean_b sum_j (ccol_j / pcol_j), ccol/pcol from slab sums.

#define BATCH 64
#define NPT   1024
#define DIM   64
#define NSLAB 16
#define CKF   28.853900817779268f    // 20 * log2(e)
#define WV0F  2.0611536224e-9f       // 2^{-CK} = e^-20  (lv=0 first pass)
#define G10F  0.0009765625f          // 2^{-10}

#if __has_builtin(__builtin_amdgcn_exp2f)
#define EXP2F(x) __builtin_amdgcn_exp2f(x)
#else
#define EXP2F(x) exp2f(x)
#endif

__device__ __forceinline__ float2 h2tof2(unsigned int u) {
  return __half22float2(__builtin_bit_cast(__half2, u));
}
__device__ __forceinline__ void dec8(uint4 pk, float* f) {
  float2 t;
  t = h2tof2(pk.x); f[0] = t.x; f[1] = t.y;
  t = h2tof2(pk.y); f[2] = t.x; f[3] = t.y;
  t = h2tof2(pk.z); f[4] = t.x; f[5] = t.y;
  t = h2tof2(pk.w); f[6] = t.x; f[7] = t.y;
}
__device__ __forceinline__ void stage16(const __half* g, __half* l) {
  __builtin_amdgcn_global_load_lds(
      (const __attribute__((address_space(1))) void*)g,
      (__attribute__((address_space(3))) void*)l, 16, 0, 0);
}

// ---------------------------------------------------------------------------
// build_q: per-batch GEMM dot[i,j] = <s_i/|s_i|, t_j/|t_j|>, fp16 out.
// (unchanged known-good; 148 us. Optimize after pass structure is verified.)
// ---------------------------------------------------------------------------
__global__ __launch_bounds__(256) void build_q(
    const float* __restrict__ src, const float* __restrict__ tgt,
    __half* __restrict__ q)
{
  __shared__ float sA[DIM][68];
  __shared__ float sB[DIM][68];

  const int b    = blockIdx.x >> 8;
  const int tile = blockIdx.x & 255;
  const int i0 = (tile >> 4) << 6;
  const int j0 = (tile & 15) << 6;
  const int tid = threadIdx.x;
  const int r = tid >> 2;
  const int c = tid & 3;

  {
    const float4* p4 = (const float4*)(src + ((size_t)b * NPT + (i0 + r)) * DIM + c * 16);
    float4 a0 = p4[0], a1 = p4[1], a2 = p4[2], a3 = p4[3];
    float v[16] = {a0.x,a0.y,a0.z,a0.w, a1.x,a1.y,a1.z,a1.w,
                   a2.x,a2.y,a2.z,a2.w, a3.x,a3.y,a3.z,a3.w};
    float ss = 0.f;
    #pragma unroll
    for (int k = 0; k < 16; ++k) ss = fmaf(v[k], v[k], ss);
    ss += __shfl_xor(ss, 1);
    ss += __shfl_xor(ss, 2);
    const float sc = 1.0f / fmaxf(sqrtf(ss), 1e-12f);
    #pragma unroll
    for (int k = 0; k < 16; ++k) sA[c * 16 + k][r] = v[k] * sc;
  }
  {
    const float4* p4 = (const float4*)(tgt + ((size_t)b * NPT + (j0 + r)) * DIM + c * 16);
    float4 a0 = p4[0], a1 = p4[1], a2 = p4[2], a3 = p4[3];
    float v[16] = {a0.x,a0.y,a0.z,a0.w, a1.x,a1.y,a1.z,a1.w,
                   a2.x,a2.y,a2.z,a2.w, a3.x,a3.y,a3.z,a3.w};
    float ss = 0.f;
    #pragma unroll
    for (int k = 0; k < 16; ++k) ss = fmaf(v[k], v[k], ss);
    ss += __shfl_xor(ss, 1);
    ss += __shfl_xor(ss, 2);
    const float sc = 1.0f / fmaxf(sqrtf(ss), 1e-12f);
    #pragma unroll
    for (int k = 0; k < 16; ++k) sB[c * 16 + k][r] = v[k] * sc;
  }
  __syncthreads();

  const int mi = (tid >> 4) << 2;
  const int mj = (tid & 15) << 2;
  float acc[4][4] = {};
  #pragma unroll 16
  for (int d = 0; d < DIM; ++d) {
    const float4 a = *(const float4*)&sA[d][mi];
    const float4 t = *(const float4*)&sB[d][mj];
    const float av[4] = {a.x, a.y, a.z, a.w};
    const float tv[4] = {t.x, t.y, t.z, t.w};
    #pragma unroll
    for (int ii = 0; ii < 4; ++ii)
      #pragma unroll
      for (int jj = 0; jj < 4; ++jj)
        acc[ii][jj] = fmaf(av[ii], tv[jj], acc[ii][jj]);
  }

  #pragma unroll
  for (int ii = 0; ii < 4; ++ii) {
    __half2 h0 = __floats2half2_rn(acc[ii][0], acc[ii][1]);
    __half2 h1 = __floats2half2_rn(acc[ii][2], acc[ii][3]);
    uint2 pk = { __builtin_bit_cast(unsigned int, h0),
                 __builtin_bit_cast(unsigned int, h1) };
    *(uint2*)(q + (size_t)b * NPT * NPT
                + (size_t)(i0 + mi + ii) * NPT + (j0 + mj)) = pk;
  }
}

// ---------------------------------------------------------------------------
// sink_pass<FIRST,FINAL>: one full Sinkhorn iteration in one q-pass.
// Grid: 1024 blocks (16 slabs/batch, 64 rows each) x 256 thr.
// Wave = full row (lane owns 16 consecutive cols); LDS-staged 8-row tiles,
// double-buffered via global_load_lds; {sync; stage(t+1); compute(t)}.
// ---------------------------------------------------------------------------
template<bool FIRST, bool FINAL>
__global__ __launch_bounds__(256) void sink_pass(
    const __half* __restrict__ q,
    const float* __restrict__ partR,  // [NSLAB][BATCH][NPT] prev partials
    float* __restrict__ partW,        // [NSLAB][BATCH][NPT] this pass partials
    float* __restrict__ cpart)        // [NSLAB][BATCH][NPT] cost partials
{
  __shared__ __align__(16) __half smem[2][8][NPT];   // 2 x 16 KB

  const int b    = blockIdx.x >> 4;
  const int slab = blockIdx.x & 15;
  const int lane = threadIdx.x & 63;
  const int wave = threadIdx.x >> 6;

  // 64-row slab of this block
  const __half* qt = q + ((size_t)b << 20) + ((size_t)(slab << 6) << 10);

  // stage tile 0 first (its latency hides under the prologue)
  {
    const __half* gsrc = qt + (wave << 11) + (lane << 3);
    __half* ldst = &smem[0][0][0] + (wave << 11);
    #pragma unroll
    for (int p = 0; p < 4; ++p)
      stage16(gsrc + (p << 9), ldst + (p << 9));
  }

  // prologue: wv[k] = 2^{lv_j - CK} = G10F / (sum over slabs of partR)
  float wv[16];
  if (FIRST) {
    #pragma unroll
    for (int k = 0; k < 16; ++k) wv[k] = WV0F;
  } else {
    float sv[16] = {};
    #pragma unroll
    for (int s = 0; s < NSLAB; ++s) {
      const float4* p4 =
          (const float4*)(partR + ((size_t)((s << 6) + b) << 10) + (lane << 4));
      #pragma unroll
      for (int g4 = 0; g4 < 4; ++g4) {
        const float4 v = p4[g4];
        sv[g4 * 4 + 0] += v.x;
        sv[g4 * 4 + 1] += v.y;
        sv[g4 * 4 + 2] += v.z;
        sv[g4 * 4 + 3] += v.w;
      }
    }
    #pragma unroll
    for (int k = 0; k < 16; ++k) wv[k] = G10F / sv[k];
  }

  float acc[16] = {};
  float cacc[16];
  if (FINAL) {
    #pragma unroll
    for (int k = 0; k < 16; ++k) cacc[k] = 0.f;
  }

  #pragma unroll 2
  for (int t = 0; t < 8; ++t) {
    __syncthreads();   // implicit vmcnt(0): tile t landed; all waves synced
    if (t < 7) {       // stage tile t+1 into the other buffer (overlaps compute)
      const __half* gsrc = qt + ((size_t)(t + 1) << 13) + (wave << 11) + (lane << 3);
      __half* ldst = &smem[(t + 1) & 1][0][0] + (wave << 11);
      #pragma unroll
      for (int p = 0; p < 4; ++p)
        stage16(gsrc + (p << 9), ldst + (p << 9));
    }
    // compute tile t: wave handles tile-rows 2w, 2w+1
    #pragma unroll
    for (int rr = 0; rr < 2; ++rr) {
      const uint4* rp = (const uint4*)&smem[t & 1][(wave << 1) + rr][0] + (lane << 1);
      const uint4 pa = rp[0];
      const uint4 pb = rp[1];
      float f[16];
      dec8(pa, f);
      dec8(pb, f + 8);
      float u[16];
      #pragma unroll
      for (int k = 0; k < 16; ++k) u[k] = EXP2F(f[k] * CKF);

      float d0 = 0.f, d1 = 0.f, d2 = 0.f, d3 = 0.f;
      #pragma unroll
      for (int k = 0; k < 16; k += 4) {
        d0 = fmaf(u[k],     wv[k],     d0);
        d1 = fmaf(u[k + 1], wv[k + 1], d1);
        d2 = fmaf(u[k + 2], wv[k + 2], d2);
        d3 = fmaf(u[k + 3], wv[k + 3], d3);
      }
      float s = (d0 + d1) + (d2 + d3);
      #pragma unroll
      for (int m = 1; m <= 32; m <<= 1) s += __shfl_xor(s, m);
      const float g = G10F / s;   // 2^{lu_i}

      #pragma unroll
      for (int k = 0; k < 16; ++k) {
        acc[k] = fmaf(u[k], g, acc[k]);
        if (FINAL) cacc[k] = fmaf(u[k] * g, fmaf(f[k], -2.0f, 2.0f), cacc[k]);
      }
    }
  }

  // epilogue: cross-wave combine in LDS (overlay staging buffers), then one
  // coalesced 4KB slab-partial store per block. NO atomics.
  __syncthreads();                       // all compute done; smem reusable
  float* lp = (float*)&smem[0][0][0];    // [4][1024] floats, 16 KB
  float* lc = (float*)&smem[1][0][0];    // [4][1024] floats (FINAL only)
  #pragma unroll
  for (int k = 0; k < 16; ++k)
    lp[(wave << 10) + (lane << 4) + k] = acc[k];
  if (FINAL) {
    #pragma unroll
    for (int k = 0; k < 16; ++k)
      lc[(wave << 10) + (lane << 4) + k] = cacc[k];
  }
  __syncthreads();
  {
    const int tid = threadIdx.x;         // float4 column-group [4*tid, 4*tid+4)
    const float4* lp4 = (const float4*)lp;
    float4 p0 = lp4[(0 << 8) + tid];
    float4 p1 = lp4[(1 << 8) + tid];
    float4 p2 = lp4[(2 << 8) + tid];
    float4 p3 = lp4[(3 << 8) + tid];
    float4 s4;
    s4.x = (p0.x + p1.x) + (p2.x + p3.x);
    s4.y = (p0.y + p1.y) + (p2.y + p3.y);
    s4.z = (p0.z + p1.z) + (p2.z + p3.z);
    s4.w = (p0.w + p1.w) + (p2.w + p3.w);
    ((float4*)(partW + ((size_t)((slab << 6) + b) << 10)))[tid] = s4;
    if (FINAL) {
      const float4* lc4 = (const float4*)lc;
      float4 c0 = lc4[(0 << 8) + tid];
      float4 c1 = lc4[(1 << 8) + tid];
      float4 c2 = lc4[(2 << 8) + tid];
      float4 c3 = lc4[(3 << 8) + tid];
      float4 c4v;
      c4v.x = (c0.x + c1.x) + (c2.x + c3.x);
      c4v.y = (c0.y + c1.y) + (c2.y + c3.y);
      c4v.z = (c0.z + c1.z) + (c2.z + c3.z);
      c4v.w = (c0.w + c1.w) + (c2.w + c3.w);
      ((float4*)(cpart + ((size_t)((slab << 6) + b) << 10)))[tid] = c4v;
    }
  }
}

// ---------------------------------------------------------------------------
// final: out = 2^-10 * mean_b sum_j (ccol_j / pcol_j); slab sums inline.
// ---------------------------------------------------------------------------
__global__ __launch_bounds__(256) void final_reduce(
    const float* __restrict__ partR, const float* __restrict__ cpart,
    float* __restrict__ out)
{
  const int b   = blockIdx.x;
  const int tid = threadIdx.x;   // float4 column group
  float4 p = {0.f, 0.f, 0.f, 0.f};
  float4 c = {0.f, 0.f, 0.f, 0.f};
  #pragma unroll 4
  for (int s = 0; s < NSLAB; ++s) {
    const size_t base = (size_t)((s << 6) + b) << 8;   // in float4 units
    const float4 pv = ((const float4*)partR)[base + tid];
    const float4 cv = ((const float4*)cpart)[base + tid];
    p.x += pv.x; p.y += pv.y; p.z += pv.z; p.w += pv.w;
    c.x += cv.x; c.y += cv.y; c.z += cv.z; c.w += cv.w;
  }
  float s = (c.x / p.x + c.y / p.y) + (c.z / p.z + c.w / p.w);
  #pragma unroll
  for (int m = 1; m <= 32; m <<= 1) s += __shfl_xor(s, m);
  __shared__ float ls[4];
  if ((threadIdx.x & 63) == 0) ls[threadIdx.x >> 6] = s;
  __syncthreads();
  if (threadIdx.x == 0)
    atomicAdd(out, (ls[0] + ls[1] + ls[2] + ls[3]) * (1.0f / 65536.0f));
}

// ---------------------------------------------------------------------------
extern "C" void kernel_launch(void* const* d_in, const int* in_sizes, int n_in,
                              void* d_out, int out_size, void* d_ws, size_t ws_size,
                              hipStream_t stream)
{
  (void)in_sizes; (void)n_in; (void)out_size; (void)ws_size;
  const float* src = (const float*)d_in[0];
  const float* tgt = (const float*)d_in[1];

  char* ws = (char*)d_ws;
  __half* q = (__half*)ws;                                    // 128 MiB
  const size_t QB = (size_t)BATCH * NPT * NPT * sizeof(__half);
  const size_t PART_N = (size_t)NSLAB * BATCH * NPT;          // 1M floats = 4 MiB
  float* partA = (float*)(ws + QB);
  float* partB = partA + PART_N;
  float* cpart = partB + PART_N;
  float* part[2] = {partA, partB};

  hipMemsetAsync(d_out, 0, sizeof(float), stream);

  build_q<<<BATCH * 256, 256, 0, stream>>>(src, tgt, q);

  for (int t = 0; t < 50; ++t) {
    float* R = part[t & 1];          // read (t>0)
    float* W = part[(t + 1) & 1];    // write
    if (t == 0)
      sink_pass<true, false><<<BATCH * NSLAB, 256, 0, stream>>>(q, nullptr, W, nullptr);
    else if (t == 49)
      sink_pass<false, true><<<BATCH * NSLAB, 256, 0, stream>>>(q, R, W, cpart);
    else
      sink_pass<false, false><<<BATCH * NSLAB, 256, 0, stream>>>(q, R, W, nullptr);
  }

  final_reduce<<<BATCH, 256, 0, stream>>>(part[0], cpart, (float*)d_out);
}